// Round 5
// baseline (1380.627 us; speedup 1.0000x reference)
//
#include <hip/hip_runtime.h>
#include <type_traits>
#include <cstdint>
#include <cstddef>

#define L_SEQ 4800
#define DMODEL 256
#define BS 8
#define MROWS (BS*L_SEQ)          // 38400
#define PERBATCH (L_SEQ*DMODEL)   // 1228800
#define KVSET 67584               // 65536 KV + 2048 Ksum floats per mode

typedef __attribute__((ext_vector_type(8))) short bfrag8;
typedef __attribute__((ext_vector_type(4))) float floatx4;

// ---------- helpers ----------
__device__ __forceinline__ float bf2f(unsigned short u){
  union { unsigned int i; float f; } x; x.i = ((unsigned int)u) << 16; return x.f;
}
__device__ __forceinline__ unsigned short f2bf(float f){
  union { float f; unsigned int i; } x; x.f = f;
  x.i += 0x7fff + ((x.i >> 16) & 1);   // RNE
  return (unsigned short)(x.i >> 16);
}
__device__ __forceinline__ float phi(float x){
  return x > 0.f ? x + 1.f : __expf(x);
}
__device__ __forceinline__ void gll16(const void* g, void* l){
  __builtin_amdgcn_global_load_lds((const __attribute__((address_space(1))) unsigned int*)g,
      (__attribute__((address_space(3))) unsigned int*)l, 16, 0, 0);
}

// ---------- MFMA GEMM (projections): C[M,N] = A[M,K] @ Bt[N,K]^T ----------
template<typename TC, bool RELU>
__global__ __launch_bounds__(256) void gemm_mfma(const unsigned short* __restrict__ A,
                                                 const unsigned short* __restrict__ Bt,
                                                 TC* __restrict__ C, int M, int N, int K){
  __shared__ unsigned short Al[2][4096];   // [buf][128 rows][32 k]
  __shared__ unsigned short Bl[2][4096];
  const int tid  = threadIdx.x;
  const int lane = tid & 63;
  const int wave = tid >> 6;
  const int row0 = blockIdx.y << 7;
  const int col0 = blockIdx.x << 7;
  const int wr0  = (wave & 1) << 6;
  const int wc0  = (wave >> 1) << 6;
  const int m = lane & 15, q = lane >> 4;
  const int sw = (m >> 1) & 3;

  floatx4 acc[4][4] = {};

  const int u0 = tid, u1 = tid + 256;
  const int r0 = u0 >> 2, s0 = u0 & 3;
  const int r1 = u1 >> 2, s1 = u1 & 3;

  auto stage = [&](int k0, int b){
    gll16(A  + (size_t)(row0 + r0)*K + k0 + ((s0 ^ ((r0 >> 1) & 3)) << 3), Al[b] + (size_t)u0*8);
    gll16(A  + (size_t)(row0 + r1)*K + k0 + ((s1 ^ ((r1 >> 1) & 3)) << 3), Al[b] + (size_t)u1*8);
    gll16(Bt + (size_t)(col0 + r0)*K + k0 + ((s0 ^ ((r0 >> 1) & 3)) << 3), Bl[b] + (size_t)u0*8);
    gll16(Bt + (size_t)(col0 + r1)*K + k0 + ((s1 ^ ((r1 >> 1) & 3)) << 3), Bl[b] + (size_t)u1*8);
  };

  stage(0, 0);
  const int nk = K >> 5;
  for (int ks = 0; ks < nk; ks++){
    asm volatile("s_waitcnt vmcnt(0) lgkmcnt(0)" ::: "memory");
    __builtin_amdgcn_s_barrier();
    asm volatile("" ::: "memory");
    if (ks < nk - 1) stage((ks + 1) << 5, (ks + 1) & 1);
    const unsigned short* ab = Al[ks & 1];
    const unsigned short* bb = Bl[ks & 1];
    bfrag8 af[4], bf[4];
    #pragma unroll
    for (int t = 0; t < 4; t++){
      af[t] = *(const bfrag8*)(ab + (size_t)(wr0 + t*16 + m)*32 + ((q ^ sw) << 3));
      bf[t] = *(const bfrag8*)(bb + (size_t)(wc0 + t*16 + m)*32 + ((q ^ sw) << 3));
    }
    #pragma unroll
    for (int mt = 0; mt < 4; mt++)
      #pragma unroll
      for (int nt = 0; nt < 4; nt++)
        acc[mt][nt] = __builtin_amdgcn_mfma_f32_16x16x32_bf16(af[mt], bf[nt], acc[mt][nt], 0, 0, 0);
  }

  #pragma unroll
  for (int mt = 0; mt < 4; mt++){
    #pragma unroll
    for (int nt = 0; nt < 4; nt++){
      const int col  = col0 + wc0 + nt*16 + m;
      const int rowb = row0 + wr0 + mt*16 + q*4;
      #pragma unroll
      for (int i = 0; i < 4; i++){
        float v = acc[mt][nt][i];
        if (RELU) v = v > 0.f ? v : 0.f;
        if constexpr (std::is_same<TC,float>::value) C[(size_t)(rowb+i)*N + col] = v;
        else                                         C[(size_t)(rowb+i)*N + col] = f2bf(v);
      }
    }
  }
}

// ---------- one-time converts ----------
__global__ __launch_bounds__(256) void wconv(const float* __restrict__ W, unsigned short* __restrict__ Wt,
                                             int kshift, int N){
  int idx = blockIdx.x*256 + threadIdx.x;
  int kk = idx & ((1 << kshift) - 1);
  int nn = idx >> kshift;
  Wt[idx] = f2bf(W[(size_t)kk*N + nn]);
}
__global__ __launch_bounds__(256) void conv_bf16(const float* __restrict__ in, unsigned short* __restrict__ out){
  int i = blockIdx.x*256 + threadIdx.x;
  float4 v = ((const float4*)in)[i];
  ushort4 o; o.x = f2bf(v.x); o.y = f2bf(v.y); o.z = f2bf(v.z); o.w = f2bf(v.w);
  ((ushort4*)out)[i] = o;
}

// ---------- permute materializers ----------
__global__ __launch_bounds__(256) void permute1(const unsigned short* __restrict__ sA, unsigned short* __restrict__ dA,
                                                const unsigned short* __restrict__ sB, unsigned short* __restrict__ dB){
  const unsigned short* s = blockIdx.z ? sB : sA;
  unsigned short*       d = blockIdx.z ? dB : dA;
  __shared__ unsigned short tile[1024];
  const int t = threadIdx.x;
  const size_t base = (size_t)blockIdx.x * 1024;
  #pragma unroll
  for (int i = 0; i < 4; i++) tile[i*256 + t] = s[base + i*256 + t];
  __syncthreads();
  const int pg = ((t & 7) << 5) + (t >> 3);
  #pragma unroll
  for (int i = 0; i < 4; i++) d[base + i*256 + t] = tile[i*256 + pg];
}

__global__ __launch_bounds__(256) void permute2(const unsigned short* __restrict__ sA, unsigned short* __restrict__ dA,
                                                const unsigned short* __restrict__ sB, unsigned short* __restrict__ dB){
  const unsigned short* s = blockIdx.z ? sB : sA;
  unsigned short*       d = blockIdx.z ? dB : dA;
  __shared__ unsigned short tile[64*256];
  const int t = threadIdx.x;
  const int rr0 = blockIdx.x * 64;
  const size_t boff = (size_t)blockIdx.y * PERBATCH;
  #pragma unroll
  for (int i = 0; i < 16; i++){
    int u = i*256 + t;
    *(ushort4*)&tile[u*4] = *(const ushort4*)&s[boff + (size_t)rr0*256 + (size_t)u*4];
  }
  __syncthreads();
  #pragma unroll
  for (int i = 0; i < 8; i++){
    #pragma unroll
    for (int w = 0; w < 2; w++){
      int u = w*256 + t;
      int rr = u >> 3, c4 = (u & 7) << 2;
      ushort4 v = *(const ushort4*)&tile[rr*256 + i*32 + c4];
      *(ushort4*)&d[boff + (size_t)i*153600 + (size_t)rr0*32 + (size_t)u*4] = v;
    }
  }
}

__global__ __launch_bounds__(256) void permute3(const unsigned short* __restrict__ sA, unsigned short* __restrict__ dA,
                                                const unsigned short* __restrict__ sB, unsigned short* __restrict__ dB){
  const unsigned short* s = blockIdx.z ? sB : sA;
  unsigned short*       d = blockIdx.z ? dB : dA;
  __shared__ unsigned short tile[64*258];
  const int t = threadIdx.x;
  const int ll0 = blockIdx.x * 64;
  const size_t boff = (size_t)blockIdx.y * PERBATCH;
  #pragma unroll
  for (int i = 0; i < 32; i++){
    int u = i*256 + t;
    int row = u >> 7, col = (u & 127) << 1;
    *(ushort2*)&tile[row*258 + col] = *(const ushort2*)&s[boff + (size_t)(ll0+row)*256 + col];
  }
  __syncthreads();
  const int cw = t >> 6;
  const int ll = t & 63;
  #pragma unroll
  for (int cc = 0; cc < 256; cc += 4){
    int c = cc + cw;
    int sigma = ((c & 31) << 3) + (c >> 5);
    d[boff + (size_t)sigma*4800 + ll0 + ll] = tile[ll*258 + c];
  }
}

// ---------- attention phase A (KV/Ksum stats) ----------
__global__ __launch_bounds__(256) void attn_stats(const unsigned short* __restrict__ kq,
                                                  const unsigned short* __restrict__ vq,
                                                  float* __restrict__ KV, float* __restrict__ Ksum){
  const int chunk = blockIdx.x, h = blockIdx.y, n = blockIdx.z;
  const int t = threadIdx.x;
  const int d = t >> 3;
  const int w4 = (t & 7) << 2;
  const size_t boff = (size_t)n * PERBATCH;
  __shared__ float kb[8][32], vb[8][32];
  const int lr = t >> 5, lj = t & 31;
  float a0=0.f, a1=0.f, a2=0.f, a3=0.f, ks=0.f;
  const int s0 = chunk * 240;
  for (int s = s0; s < s0 + 240; s += 8){
    int srci = (s + lr)*256 + (h << 5) + lj;
    kb[lr][lj] = phi(bf2f(kq[boff + srci]));
    vb[lr][lj] = bf2f(vq[boff + srci]);
    __syncthreads();
    #pragma unroll
    for (int r = 0; r < 8; r++){
      float kd = kb[r][d];
      ks += kd;
      a0 += kd * vb[r][w4+0];
      a1 += kd * vb[r][w4+1];
      a2 += kd * vb[r][w4+2];
      a3 += kd * vb[r][w4+3];
    }
    __syncthreads();
  }
  float* kvp = KV + (size_t)((((n<<3)+h)<<5) + d)*32 + w4;
  atomicAdd(kvp+0, a0);
  atomicAdd(kvp+1, a1);
  atomicAdd(kvp+2, a2);
  atomicAdd(kvp+3, a3);
  if ((t & 7) == 0) atomicAdd(Ksum + (((n<<3)+h)<<5) + d, ks);
}

// ---------- fused attention apply + Wm GEMM + LN -> hcat right half ----------
__global__ __launch_bounds__(256) void attn_fused(const unsigned short* __restrict__ qq,
                                                  const float* __restrict__ KV,
                                                  const float* __restrict__ Ksum,
                                                  const unsigned short* __restrict__ WmT,
                                                  const float* __restrict__ g1,
                                                  const float* __restrict__ b1,
                                                  unsigned short* __restrict__ hcat){
  __shared__ float kvs[8192];      // 32KB [h][d][w]
  __shared__ float Qs[4096];       // 16KB [16][256] phi-applied
  __shared__ float kss[256];       // 1KB
  __shared__ char  msgL[8192];     // [16 rows][512B], XOR key (row&7)<<4
  __shared__ float2 LNp[16][4];
  const int t = threadIdx.x;
  const int n = blockIdx.y;
  const int row0 = blockIdx.x << 4;
  const size_t boff = (size_t)n * PERBATCH;

  {
    const float4* kvsrc = (const float4*)(KV + (size_t)n*8192);
    #pragma unroll
    for (int i = 0; i < 8; i++) ((float4*)kvs)[i*256 + t] = kvsrc[i*256 + t];
    kss[t] = Ksum[n*256 + t];
    #pragma unroll
    for (int i = 0; i < 4; i++){
      int u = (i << 8) + t;
      int r = u >> 6, c4 = (u & 63) << 2;
      ushort4 v = *(const ushort4*)(qq + boff + (size_t)(row0 + r)*256 + c4);
      float4 f;
      f.x = phi(bf2f(v.x)); f.y = phi(bf2f(v.y)); f.z = phi(bf2f(v.z)); f.w = phi(bf2f(v.w));
      *(float4*)&Qs[r*256 + c4] = f;
    }
  }
  __syncthreads();

  // ---- phase A: msg[16][256] ----
  {
    const int h = t >> 5, w = t & 31;
    const float* kvh = kvs + h*1024;
    const float* ksh = kss + h*32;
    float acc[16], den[16];
    #pragma unroll
    for (int r = 0; r < 16; r++){ acc[r] = 0.f; den[r] = 1e-6f; }
    #pragma unroll
    for (int d4 = 0; d4 < 8; d4++){
      const float k0 = kvh[(d4*4+0)*32 + w];
      const float k1 = kvh[(d4*4+1)*32 + w];
      const float k2 = kvh[(d4*4+2)*32 + w];
      const float k3 = kvh[(d4*4+3)*32 + w];
      const float s0 = ksh[d4*4+0], s1 = ksh[d4*4+1], s2 = ksh[d4*4+2], s3 = ksh[d4*4+3];
      #pragma unroll
      for (int r = 0; r < 16; r++){
        float4 qv = *(const float4*)&Qs[r*256 + h*32 + d4*4];
        acc[r] += qv.x*k0 + qv.y*k1 + qv.z*k2 + qv.w*k3;
        den[r] += qv.x*s0 + qv.y*s1 + qv.z*s2 + qv.w*s3;
      }
    }
    #pragma unroll
    for (int r = 0; r < 16; r++){
      int byte = (r << 9) + ((t << 1) ^ ((r & 7) << 4));
      *(unsigned short*)(msgL + byte) = f2bf(acc[r] / den[r]);
    }
  }
  __syncthreads();

  // ---- phase B: out[16][256] = msg @ WmT^T, B-frags direct from global ----
  const int wv = t >> 6, lane = t & 63, m = lane & 15, qd = lane >> 4;
  floatx4 Cf[4] = {};
  #pragma unroll
  for (int ks = 0; ks < 8; ks++){
    int abyte = m*512 + ((ks*64 + qd*16) ^ ((m & 7) << 4));
    bfrag8 af = *(const bfrag8*)(msgL + abyte);
    #pragma unroll
    for (int nt = 0; nt < 4; nt++){
      int col = wv*64 + nt*16 + m;
      bfrag8 bf = *(const bfrag8*)(WmT + (size_t)col*256 + ks*32 + qd*8);
      Cf[nt] = __builtin_amdgcn_mfma_f32_16x16x32_bf16(af, bf, Cf[nt], 0, 0, 0);
    }
  }

  // ---- LN (cross-wave partial merge over 4 col-quarters) ----
  #pragma unroll
  for (int i = 0; i < 4; i++){
    float s = 0.f, q = 0.f;
    #pragma unroll
    for (int nt = 0; nt < 4; nt++){ float v = Cf[nt][i]; s += v; q += v*v; }
    #pragma unroll
    for (int o = 1; o < 16; o <<= 1){ s += __shfl_xor(s, o, 64); q += __shfl_xor(q, o, 64); }
    if (m == 0) LNp[qd*4 + i][wv] = make_float2(s, q);
  }
  __syncthreads();
  float gv[4], bv[4];
  #pragma unroll
  for (int nt = 0; nt < 4; nt++){ int col = wv*64 + nt*16 + m; gv[nt] = g1[col]; bv[nt] = b1[col]; }
  #pragma unroll
  for (int i = 0; i < 4; i++){
    int row = qd*4 + i;
    float2 p0 = LNp[row][0], p1 = LNp[row][1], p2 = LNp[row][2], p3 = LNp[row][3];
    float S = p0.x + p1.x + p2.x + p3.x;
    float Q = p0.y + p1.y + p2.y + p3.y;
    float mu = S * (1.f/256.f);
    float rs = rsqrtf(Q * (1.f/256.f) - mu*mu + 1e-5f);
    #pragma unroll
    for (int nt = 0; nt < 4; nt++){
      int col = wv*64 + nt*16 + m;
      *(unsigned short*)(msgL + row*512 + col*2) = f2bf((Cf[nt][i] - mu) * rs * gv[nt] + bv[nt]);
    }
  }
  __syncthreads();
  const size_t gbase = ((size_t)n*4800 + row0)*512 + 256;
  #pragma unroll
  for (int i = 0; i < 4; i++){
    int u = (i << 8) + t;
    int r = u >> 6, c4 = (u & 63) << 2;
    *(ushort4*)(hcat + gbase + (size_t)r*512 + c4) = *(const ushort4*)(msgL + r*512 + c4*2);
  }
}

// ---------- fused FFN v5: macc (+)= LN(relu(hcat@W1)@W2) ----------
// grid 1200, 512 threads (8 waves), 32 rows/block. LDS ~67KB -> 2 blocks/CU, NO launch-bounds cap.
// A staged once (source-swizzled gll16); B direct from L2-resident W1T/W2T; 3 barriers total.
__global__ __launch_bounds__(512) void ffn_fused(const unsigned short* __restrict__ hcat,
                                                 const unsigned short* __restrict__ W1T,
                                                 const unsigned short* __restrict__ W2T,
                                                 const float* __restrict__ g2,
                                                 const float* __restrict__ b2,
                                                 float* __restrict__ macc, int add){
  __shared__ char hcatS[32768];    // [32 rows][64 slots x16B], src-swizzled: slot ^= row&7
  __shared__ char hidL[32768];     // 16 chunks x [32 rows][32 k] bf16, slot swizzle (row>>1)&3
  __shared__ float2 LNp[32][4];
  __shared__ float2 LNmu[32];
  const int tid = threadIdx.x;
  const int wv = tid >> 6, lane = tid & 63;
  const int m = lane & 15, qd = lane >> 4;
  const int row0 = blockIdx.x << 5;

  // ---- stage A tile once (32x512 bf16 = 32KB), pre-swizzled source ----
  #pragma unroll
  for (int p = 0; p < 4; p++){
    int u = (p << 9) + tid;
    int r = u >> 6, slot = u & 63;
    gll16(hcat + (size_t)(row0 + r)*512 + ((slot ^ (r & 7)) << 3), hcatS + (u << 4));
  }
  asm volatile("s_waitcnt vmcnt(0)" ::: "memory");
  __syncthreads();

  // ---- phase 1: hid[32][512] = relu(A @ W1). wave wv -> cols [wv*64, wv*64+64) ----
  floatx4 acc1[2][4] = {};
  {
    const unsigned short* Bb = W1T + (size_t)(wv*64 + m)*512 + qd*8;
    for (int ks = 0; ks < 16; ks++){
      bfrag8 af[2], bf[4];
      #pragma unroll
      for (int t = 0; t < 2; t++){
        int row = t*16 + m;
        af[t] = *(const bfrag8*)(hcatS + row*1024 + (((ks*4 + qd) ^ (row & 7)) << 4));
      }
      #pragma unroll
      for (int nt = 0; nt < 4; nt++)
        bf[nt] = *(const bfrag8*)(Bb + (size_t)(nt*16)*512 + ks*32);
      #pragma unroll
      for (int mt = 0; mt < 2; mt++)
        #pragma unroll
        for (int nt = 0; nt < 4; nt++)
          acc1[mt][nt] = __builtin_amdgcn_mfma_f32_16x16x32_bf16(af[mt], bf[nt], acc1[mt][nt], 0, 0, 0);
    }
  }

  // relu + store hid to LDS (wave wv owns hid cols [wv*64,+64) = chunks 2wv, 2wv+1)
  #pragma unroll
  for (int nt = 0; nt < 4; nt++){
    const int c  = wv*2 + (nt >> 1);
    const int kl = ((nt & 1) << 4) + m;
    const int slot = kl >> 3;
    #pragma unroll
    for (int mt = 0; mt < 2; mt++)
      #pragma unroll
      for (int i = 0; i < 4; i++){
        int row = mt*16 + qd*4 + i;
        float v = acc1[mt][nt][i];
        v = v > 0.f ? v : 0.f;
        int byte = (c << 11) + row*64 + ((slot ^ ((row >> 1) & 3)) << 4) + ((kl & 7) << 1);
        *(unsigned short*)(hidL + byte) = f2bf(v);
      }
  }
  __syncthreads();

  // ---- phase 2: out[32][256] = hid @ W2. wave: rows (wv&1)*16, cols (wv>>1)*64 ----
  const int wr = wv & 1, cg = wv >> 1;
  floatx4 acc2[4] = {};
  {
    const unsigned short* Bb = W2T + (size_t)(cg*64 + m)*512 + qd*8;
    const int row = wr*16 + m;
    const int sw2 = (row >> 1) & 3;
    for (int ks = 0; ks < 16; ks++){
      bfrag8 af = *(const bfrag8*)(hidL + (ks << 11) + row*64 + ((qd ^ sw2) << 4));
      #pragma unroll
      for (int nt = 0; nt < 4; nt++){
        bfrag8 bf = *(const bfrag8*)(Bb + (size_t)(nt*16)*512 + ks*32);
        acc2[nt] = __builtin_amdgcn_mfma_f32_16x16x32_bf16(af, bf, acc2[nt], 0, 0, 0);
      }
    }
  }

  // ---- LN epilogue ----
  #pragma unroll
  for (int i = 0; i < 4; i++){
    float s = 0.f, q = 0.f;
    #pragma unroll
    for (int nt = 0; nt < 4; nt++){ float v = acc2[nt][i]; s += v; q += v*v; }
    #pragma unroll
    for (int o = 1; o < 16; o <<= 1){ s += __shfl_xor(s, o, 64); q += __shfl_xor(q, o, 64); }
    if (m == 0) LNp[wr*16 + qd*4 + i][cg] = make_float2(s, q);
  }
  __syncthreads();
  if (tid < 32){
    float S = 0.f, Q = 0.f;
    #pragma unroll
    for (int j = 0; j < 4; j++){ float2 p = LNp[tid][j]; S += p.x; Q += p.y; }
    float mean = S * (1.f/256.f);
    float var  = Q * (1.f/256.f) - mean*mean;
    LNmu[tid] = make_float2(mean, rsqrtf(var + 1e-5f));
  }
  __syncthreads();
  float gv[4], bv[4];
  #pragma unroll
  for (int nt = 0; nt < 4; nt++){ int col = cg*64 + nt*16 + m; gv[nt] = g2[col]; bv[nt] = b2[col]; }
  #pragma unroll
  for (int i = 0; i < 4; i++){
    int row = wr*16 + qd*4 + i;
    float2 ms = LNmu[row];
    #pragma unroll
    for (int nt = 0; nt < 4; nt++){
      float y = (acc2[nt][i] - ms.x) * ms.y * gv[nt] + bv[nt];
      float* p = macc + (size_t)(row0 + row)*256 + cg*64 + nt*16 + m;
      if (add) y += *p;
      *p = y;
    }
  }
}

// ---------- elementwise ----------
__global__ __launch_bounds__(256) void fill_hcat(const float* __restrict__ x, unsigned short* __restrict__ hcat){
  size_t i = (size_t)blockIdx.x*256 + threadIdx.x;
  hcat[(i >> 8)*512 + (i & 255)] = f2bf(x[i]);
}
__global__ __launch_bounds__(256) void xmid_k(const float* __restrict__ x, const float* __restrict__ macc,
                                              float* __restrict__ xmid, unsigned short* __restrict__ hcat){
  size_t i = (size_t)blockIdx.x*256 + threadIdx.x;
  float v = x[i] + 0.5f*macc[i];
  xmid[i] = v;
  hcat[(i >> 8)*512 + (i & 255)] = f2bf(v);
}
__global__ __launch_bounds__(256) void final_k(float* __restrict__ out, const float* __restrict__ macc){
  size_t i = (size_t)blockIdx.x*256 + threadIdx.x;
  out[i] = out[i] + 0.5f*macc[i];
}
__global__ __launch_bounds__(256) void zero_k(float* __restrict__ p, int n){
  int i = blockIdx.x*256 + threadIdx.x;
  if (i < n) p[i] = 0.f;
}

// ---------- orchestration ----------
extern "C" void kernel_launch(void* const* d_in, const int* in_sizes, int n_in,
                              void* d_out, int out_size, void* d_ws, size_t ws_size,
                              hipStream_t stream){
  const float* x   = (const float*)d_in[0];
  const float* src = (const float*)d_in[1];
  const float* Wq  = (const float*)d_in[2];
  const float* Wk  = (const float*)d_in[3];
  const float* Wv  = (const float*)d_in[4];
  const float* Wm  = (const float*)d_in[5];
  const float* W1  = (const float*)d_in[6];
  const float* W2  = (const float*)d_in[7];
  const float* g1  = (const float*)d_in[8];
  const float* b1  = (const float*)d_in[9];
  const float* g2  = (const float*)d_in[10];
  const float* b2  = (const float*)d_in[11];
  float* out = (float*)d_out;

  char* ws = (char*)d_ws;
  size_t off = 0;
  auto alloc = [&](size_t bytes) -> void* {
    void* p = ws + off;
    off += (bytes + 255) & ~(size_t)255;
    return p;
  };
  unsigned short* qB    = (unsigned short*)alloc((size_t)MROWS*256*2);
  unsigned short* kB    = (unsigned short*)alloc((size_t)MROWS*256*2);
  unsigned short* vB    = (unsigned short*)alloc((size_t)MROWS*256*2);
  unsigned short* hcatB = (unsigned short*)alloc((size_t)MROWS*512*2);
  float* t1   = (float*)alloc((size_t)MROWS*256*4);
  float* macc = (float*)alloc((size_t)MROWS*256*4);
  float* KV4  = (float*)alloc((size_t)4*KVSET*4);
  unsigned short* WqT = (unsigned short*)alloc((size_t)256*256*2);
  unsigned short* WkT = (unsigned short*)alloc((size_t)256*256*2);
  unsigned short* WvT = (unsigned short*)alloc((size_t)256*256*2);
  unsigned short* WmT = (unsigned short*)alloc((size_t)256*256*2);
  unsigned short* W1T = (unsigned short*)alloc((size_t)512*512*2);
  unsigned short* W2T = (unsigned short*)alloc((size_t)256*512*2);
  (void)ws_size; (void)in_sizes; (void)n_in; (void)out_size;

  unsigned short* srcbf = (unsigned short*)t1;
  unsigned short* xbf   = srcbf + (size_t)MROWS*256;
  unsigned short* qP    = (unsigned short*)t1;
  unsigned short* kP    = (unsigned short*)macc;
  unsigned short* vP    = kP + (size_t)MROWS*256;
  float* xmid = out;

  const dim3 blk(256);

  wconv<<<dim3(256),  blk, 0, stream>>>(Wq, WqT, 8, 256);
  wconv<<<dim3(256),  blk, 0, stream>>>(Wk, WkT, 8, 256);
  wconv<<<dim3(256),  blk, 0, stream>>>(Wv, WvT, 8, 256);
  wconv<<<dim3(256),  blk, 0, stream>>>(Wm, WmT, 8, 256);
  wconv<<<dim3(1024), blk, 0, stream>>>(W1, W1T, 9, 512);
  wconv<<<dim3(512),  blk, 0, stream>>>(W2, W2T, 9, 256);
  conv_bf16<<<dim3(9600), blk, 0, stream>>>(src, srcbf);
  conv_bf16<<<dim3(9600), blk, 0, stream>>>(x,   xbf);

  gemm_mfma<unsigned short, false><<<dim3(2,300), blk, 0, stream>>>(xbf,   WqT, qB, MROWS, 256, 256);
  gemm_mfma<unsigned short, false><<<dim3(2,300), blk, 0, stream>>>(srcbf, WkT, kB, MROWS, 256, 256);
  gemm_mfma<unsigned short, false><<<dim3(2,300), blk, 0, stream>>>(srcbf, WvT, vB, MROWS, 256, 256);

  zero_k<<<dim3(1056), blk, 0, stream>>>(KV4, 4*KVSET);
  attn_stats<<<dim3(20,8,8), blk, 0, stream>>>(kB, vB, KV4 + 0*KVSET, KV4 + 0*KVSET + 65536);
  permute1<<<dim3(9600,1,2), blk, 0, stream>>>(kB, kP, vB, vP);
  attn_stats<<<dim3(20,8,8), blk, 0, stream>>>(kP, vP, KV4 + 1*KVSET, KV4 + 1*KVSET + 65536);
  permute2<<<dim3(75,8,2),  blk, 0, stream>>>(kB, kP, vB, vP);
  attn_stats<<<dim3(20,8,8), blk, 0, stream>>>(kP, vP, KV4 + 2*KVSET, KV4 + 2*KVSET + 65536);
  permute3<<<dim3(75,8,2),  blk, 0, stream>>>(kB, kP, vB, vP);
  attn_stats<<<dim3(20,8,8), blk, 0, stream>>>(kP, vP, KV4 + 3*KVSET, KV4 + 3*KVSET + 65536);

  fill_hcat<<<dim3(MROWS), blk, 0, stream>>>(x, hcatB);

  auto run_block = [&](int mode, int add){
    const float* KV   = KV4 + (size_t)mode*KVSET;
    const float* Ksum = KV + 65536;
    const unsigned short* qsrc = qB;
    if (mode == 1){ permute1<<<dim3(9600,1,1), blk, 0, stream>>>(qB, qP, nullptr, nullptr); qsrc = qP; }
    else if (mode == 2){ permute2<<<dim3(75,8,1), blk, 0, stream>>>(qB, qP, nullptr, nullptr); qsrc = qP; }
    else if (mode == 3){ permute3<<<dim3(75,8,1), blk, 0, stream>>>(qB, qP, nullptr, nullptr); qsrc = qP; }
    attn_fused<<<dim3(300,BS), blk, 0, stream>>>(qsrc, KV, Ksum, WmT, g1, b1, hcatB);
    ffn_fused<<<dim3(1200), dim3(512), 0, stream>>>(hcatB, W1T, W2T, g2, b2, macc, add);
  };

  run_block(0, 0);   // m   (identity)
  run_block(1, 1);   // m3  (p13)
  xmid_k<<<dim3(MROWS), blk, 0, stream>>>(x, macc, xmid, hcatB);
  run_block(2, 0);   // m1  (p21)
  run_block(3, 1);   // m2  (p32)
  final_k<<<dim3(MROWS), blk, 0, stream>>>(out, macc);
}

// Round 6
// 1010.809 us; speedup vs baseline: 1.3659x; 1.3659x over previous
//
#include <hip/hip_runtime.h>
#include <type_traits>
#include <cstdint>
#include <cstddef>

#define L_SEQ 4800
#define DMODEL 256
#define BS 8
#define MROWS (BS*L_SEQ)          // 38400
#define PERBATCH (L_SEQ*DMODEL)   // 1228800
#define KVSET 67584               // 65536 KV + 2048 Ksum floats per mode

typedef __attribute__((ext_vector_type(8))) short bfrag8;
typedef __attribute__((ext_vector_type(4))) float floatx4;

// ---------- helpers ----------
__device__ __forceinline__ float bf2f(unsigned short u){
  union { unsigned int i; float f; } x; x.i = ((unsigned int)u) << 16; return x.f;
}
__device__ __forceinline__ unsigned short f2bf(float f){
  union { float f; unsigned int i; } x; x.f = f;
  x.i += 0x7fff + ((x.i >> 16) & 1);   // RNE
  return (unsigned short)(x.i >> 16);
}
__device__ __forceinline__ float phi(float x){
  return x > 0.f ? x + 1.f : __expf(x);
}
__device__ __forceinline__ void gll16(const void* g, void* l){
  __builtin_amdgcn_global_load_lds((const __attribute__((address_space(1))) unsigned int*)g,
      (__attribute__((address_space(3))) unsigned int*)l, 16, 0, 0);
}

// ---------- MFMA GEMM (projections + W1): C[M,N] = act(A[M,K] @ Bt[N,K]^T) ----------
template<typename TC, bool RELU>
__global__ __launch_bounds__(256) void gemm_mfma(const unsigned short* __restrict__ A,
                                                 const unsigned short* __restrict__ Bt,
                                                 TC* __restrict__ C, int M, int N, int K){
  __shared__ unsigned short Al[2][4096];   // [buf][128 rows][32 k]
  __shared__ unsigned short Bl[2][4096];
  const int tid  = threadIdx.x;
  const int lane = tid & 63;
  const int wave = tid >> 6;
  const int row0 = blockIdx.y << 7;
  const int col0 = blockIdx.x << 7;
  const int wr0  = (wave & 1) << 6;
  const int wc0  = (wave >> 1) << 6;
  const int m = lane & 15, q = lane >> 4;
  const int sw = (m >> 1) & 3;

  floatx4 acc[4][4] = {};

  const int u0 = tid, u1 = tid + 256;
  const int r0 = u0 >> 2, s0 = u0 & 3;
  const int r1 = u1 >> 2, s1 = u1 & 3;

  auto stage = [&](int k0, int b){
    gll16(A  + (size_t)(row0 + r0)*K + k0 + ((s0 ^ ((r0 >> 1) & 3)) << 3), Al[b] + (size_t)u0*8);
    gll16(A  + (size_t)(row0 + r1)*K + k0 + ((s1 ^ ((r1 >> 1) & 3)) << 3), Al[b] + (size_t)u1*8);
    gll16(Bt + (size_t)(col0 + r0)*K + k0 + ((s0 ^ ((r0 >> 1) & 3)) << 3), Bl[b] + (size_t)u0*8);
    gll16(Bt + (size_t)(col0 + r1)*K + k0 + ((s1 ^ ((r1 >> 1) & 3)) << 3), Bl[b] + (size_t)u1*8);
  };

  stage(0, 0);
  const int nk = K >> 5;
  for (int ks = 0; ks < nk; ks++){
    asm volatile("s_waitcnt vmcnt(0) lgkmcnt(0)" ::: "memory");
    __builtin_amdgcn_s_barrier();
    asm volatile("" ::: "memory");
    if (ks < nk - 1) stage((ks + 1) << 5, (ks + 1) & 1);
    const unsigned short* ab = Al[ks & 1];
    const unsigned short* bb = Bl[ks & 1];
    bfrag8 af[4], bf[4];
    #pragma unroll
    for (int t = 0; t < 4; t++){
      af[t] = *(const bfrag8*)(ab + (size_t)(wr0 + t*16 + m)*32 + ((q ^ sw) << 3));
      bf[t] = *(const bfrag8*)(bb + (size_t)(wc0 + t*16 + m)*32 + ((q ^ sw) << 3));
    }
    #pragma unroll
    for (int mt = 0; mt < 4; mt++)
      #pragma unroll
      for (int nt = 0; nt < 4; nt++)
        acc[mt][nt] = __builtin_amdgcn_mfma_f32_16x16x32_bf16(af[mt], bf[nt], acc[mt][nt], 0, 0, 0);
  }

  #pragma unroll
  for (int mt = 0; mt < 4; mt++){
    #pragma unroll
    for (int nt = 0; nt < 4; nt++){
      const int col  = col0 + wc0 + nt*16 + m;
      const int rowb = row0 + wr0 + mt*16 + q*4;
      #pragma unroll
      for (int i = 0; i < 4; i++){
        float v = acc[mt][nt][i];
        if (RELU) v = v > 0.f ? v : 0.f;
        if constexpr (std::is_same<TC,float>::value) C[(size_t)(rowb+i)*N + col] = v;
        else                                         C[(size_t)(rowb+i)*N + col] = f2bf(v);
      }
    }
  }
}

// ---------- GEMM + LayerNorm epilogue: same proven inner loop, 64x256 block, 4 waves ----------
// MODE 0: outb[row*512 + 256 + col] = bf16(LN(A@Bt^T))   (Wm path -> hcat right half)
// MODE 1: outf[row*256 + col] (+)= LN(A@Bt^T)            (W2 path -> macc)
template<int MODE>
__global__ __launch_bounds__(256) void gemm_ln(const unsigned short* __restrict__ A,
                                               const unsigned short* __restrict__ Bt,
                                               const float* __restrict__ g,
                                               const float* __restrict__ b,
                                               unsigned short* __restrict__ outb,
                                               float* __restrict__ outf,
                                               int K, int add){
  __shared__ unsigned short Ab[2][2048];   // [buf][64 rows][32 k]
  __shared__ unsigned short Bb[2][8192];   // [buf][256 cols][32 k]
  __shared__ float2 LNp[64][4];
  __shared__ float2 LNmu[64];
  const int tid = threadIdx.x;
  const int wv = tid >> 6, lane = tid & 63;
  const int m = lane & 15, qd = lane >> 4;
  const int sw = (m >> 1) & 3;
  const int row0 = blockIdx.x << 6;

  const int ra = tid >> 2, sa = tid & 3;

  auto stage = [&](int k0, int bsel){
    gll16(A + (size_t)(row0 + ra)*K + k0 + ((sa ^ ((ra >> 1) & 3)) << 3), Ab[bsel] + (size_t)tid*8);
    #pragma unroll
    for (int i = 0; i < 4; i++){
      int u = (i << 8) + tid;
      int c = u >> 2, s = u & 3;
      gll16(Bt + (size_t)c*K + k0 + ((s ^ ((c >> 1) & 3)) << 3), Bb[bsel] + (size_t)u*8);
    }
  };

  floatx4 acc[4][4] = {};
  stage(0, 0);
  const int nk = K >> 5;
  for (int ks = 0; ks < nk; ks++){
    asm volatile("s_waitcnt vmcnt(0) lgkmcnt(0)" ::: "memory");
    __builtin_amdgcn_s_barrier();
    asm volatile("" ::: "memory");
    if (ks < nk - 1) stage((ks + 1) << 5, (ks + 1) & 1);
    const unsigned short* ab = Ab[ks & 1];
    const unsigned short* bb = Bb[ks & 1];
    bfrag8 af[4], bf[4];
    #pragma unroll
    for (int t = 0; t < 4; t++){
      af[t] = *(const bfrag8*)(ab + (size_t)(t*16 + m)*32 + ((qd ^ sw) << 3));
      bf[t] = *(const bfrag8*)(bb + (size_t)(wv*64 + t*16 + m)*32 + ((qd ^ sw) << 3));
    }
    #pragma unroll
    for (int mt = 0; mt < 4; mt++)
      #pragma unroll
      for (int nt = 0; nt < 4; nt++)
        acc[mt][nt] = __builtin_amdgcn_mfma_f32_16x16x32_bf16(af[mt], bf[nt], acc[mt][nt], 0, 0, 0);
  }

  // ---- LN: per-wave partials over its 64 cols, merge across 4 waves ----
  #pragma unroll
  for (int mt = 0; mt < 4; mt++)
    #pragma unroll
    for (int i = 0; i < 4; i++){
      float s = 0.f, q = 0.f;
      #pragma unroll
      for (int nt = 0; nt < 4; nt++){ float v = acc[mt][nt][i]; s += v; q += v*v; }
      #pragma unroll
      for (int o = 1; o < 16; o <<= 1){ s += __shfl_xor(s, o, 64); q += __shfl_xor(q, o, 64); }
      if (m == 0) LNp[mt*16 + qd*4 + i][wv] = make_float2(s, q);
    }
  __syncthreads();
  if (tid < 64){
    float2 p0 = LNp[tid][0], p1 = LNp[tid][1], p2 = LNp[tid][2], p3 = LNp[tid][3];
    float S = p0.x + p1.x + p2.x + p3.x;
    float Q = p0.y + p1.y + p2.y + p3.y;
    float mean = S * (1.f/256.f);
    float var  = Q * (1.f/256.f) - mean*mean;
    LNmu[tid] = make_float2(mean, rsqrtf(var + 1e-5f));
  }
  __syncthreads();

  float gv[4], bv[4];
  #pragma unroll
  for (int nt = 0; nt < 4; nt++){ int col = wv*64 + nt*16 + m; gv[nt] = g[col]; bv[nt] = b[col]; }
  #pragma unroll
  for (int mt = 0; mt < 4; mt++)
    #pragma unroll
    for (int i = 0; i < 4; i++){
      int row = mt*16 + qd*4 + i;
      float2 ms = LNmu[row];
      const size_t rowg = row0 + row;
      #pragma unroll
      for (int nt = 0; nt < 4; nt++){
        int col = wv*64 + nt*16 + m;
        float y = (acc[mt][nt][i] - ms.x) * ms.y * gv[nt] + bv[nt];
        if constexpr (MODE == 0){
          outb[rowg*512 + 256 + col] = f2bf(y);
        } else {
          float* p = outf + rowg*256 + col;
          if (add) y += *p;
          *p = y;
        }
      }
    }
}

// ---------- one-time converts ----------
__global__ __launch_bounds__(256) void wconv(const float* __restrict__ W, unsigned short* __restrict__ Wt,
                                             int kshift, int N){
  int idx = blockIdx.x*256 + threadIdx.x;
  int kk = idx & ((1 << kshift) - 1);
  int nn = idx >> kshift;
  Wt[idx] = f2bf(W[(size_t)kk*N + nn]);
}
__global__ __launch_bounds__(256) void conv_bf16(const float* __restrict__ in, unsigned short* __restrict__ out){
  int i = blockIdx.x*256 + threadIdx.x;
  float4 v = ((const float4*)in)[i];
  ushort4 o; o.x = f2bf(v.x); o.y = f2bf(v.y); o.z = f2bf(v.z); o.w = f2bf(v.w);
  ((ushort4*)out)[i] = o;
}

// ---------- permute materializers ----------
__global__ __launch_bounds__(256) void permute1(const unsigned short* __restrict__ sA, unsigned short* __restrict__ dA,
                                                const unsigned short* __restrict__ sB, unsigned short* __restrict__ dB){
  const unsigned short* s = blockIdx.z ? sB : sA;
  unsigned short*       d = blockIdx.z ? dB : dA;
  __shared__ unsigned short tile[1024];
  const int t = threadIdx.x;
  const size_t base = (size_t)blockIdx.x * 1024;
  #pragma unroll
  for (int i = 0; i < 4; i++) tile[i*256 + t] = s[base + i*256 + t];
  __syncthreads();
  const int pg = ((t & 7) << 5) + (t >> 3);
  #pragma unroll
  for (int i = 0; i < 4; i++) d[base + i*256 + t] = tile[i*256 + pg];
}

__global__ __launch_bounds__(256) void permute2(const unsigned short* __restrict__ sA, unsigned short* __restrict__ dA,
                                                const unsigned short* __restrict__ sB, unsigned short* __restrict__ dB){
  const unsigned short* s = blockIdx.z ? sB : sA;
  unsigned short*       d = blockIdx.z ? dB : dA;
  __shared__ unsigned short tile[64*256];
  const int t = threadIdx.x;
  const int rr0 = blockIdx.x * 64;
  const size_t boff = (size_t)blockIdx.y * PERBATCH;
  #pragma unroll
  for (int i = 0; i < 16; i++){
    int u = i*256 + t;
    *(ushort4*)&tile[u*4] = *(const ushort4*)&s[boff + (size_t)rr0*256 + (size_t)u*4];
  }
  __syncthreads();
  #pragma unroll
  for (int i = 0; i < 8; i++){
    #pragma unroll
    for (int w = 0; w < 2; w++){
      int u = w*256 + t;
      int rr = u >> 3, c4 = (u & 7) << 2;
      ushort4 v = *(const ushort4*)&tile[rr*256 + i*32 + c4];
      *(ushort4*)&d[boff + (size_t)i*153600 + (size_t)rr0*32 + (size_t)u*4] = v;
    }
  }
}

__global__ __launch_bounds__(256) void permute3(const unsigned short* __restrict__ sA, unsigned short* __restrict__ dA,
                                                const unsigned short* __restrict__ sB, unsigned short* __restrict__ dB){
  const unsigned short* s = blockIdx.z ? sB : sA;
  unsigned short*       d = blockIdx.z ? dB : dA;
  __shared__ unsigned short tile[64*258];
  const int t = threadIdx.x;
  const int ll0 = blockIdx.x * 64;
  const size_t boff = (size_t)blockIdx.y * PERBATCH;
  #pragma unroll
  for (int i = 0; i < 32; i++){
    int u = i*256 + t;
    int row = u >> 7, col = (u & 127) << 1;
    *(ushort2*)&tile[row*258 + col] = *(const ushort2*)&s[boff + (size_t)(ll0+row)*256 + col];
  }
  __syncthreads();
  const int cw = t >> 6;
  const int ll = t & 63;
  #pragma unroll
  for (int cc = 0; cc < 256; cc += 4){
    int c = cc + cw;
    int sigma = ((c & 31) << 3) + (c >> 5);
    d[boff + (size_t)sigma*4800 + ll0 + ll] = tile[ll*258 + c];
  }
}

// ---------- attention phase A (KV/Ksum stats) ----------
__global__ __launch_bounds__(256) void attn_stats(const unsigned short* __restrict__ kq,
                                                  const unsigned short* __restrict__ vq,
                                                  float* __restrict__ KV, float* __restrict__ Ksum){
  const int chunk = blockIdx.x, h = blockIdx.y, n = blockIdx.z;
  const int t = threadIdx.x;
  const int d = t >> 3;
  const int w4 = (t & 7) << 2;
  const size_t boff = (size_t)n * PERBATCH;
  __shared__ float kb[8][32], vb[8][32];
  const int lr = t >> 5, lj = t & 31;
  float a0=0.f, a1=0.f, a2=0.f, a3=0.f, ks=0.f;
  const int s0 = chunk * 240;
  for (int s = s0; s < s0 + 240; s += 8){
    int srci = (s + lr)*256 + (h << 5) + lj;
    kb[lr][lj] = phi(bf2f(kq[boff + srci]));
    vb[lr][lj] = bf2f(vq[boff + srci]);
    __syncthreads();
    #pragma unroll
    for (int r = 0; r < 8; r++){
      float kd = kb[r][d];
      ks += kd;
      a0 += kd * vb[r][w4+0];
      a1 += kd * vb[r][w4+1];
      a2 += kd * vb[r][w4+2];
      a3 += kd * vb[r][w4+3];
    }
    __syncthreads();
  }
  float* kvp = KV + (size_t)((((n<<3)+h)<<5) + d)*32 + w4;
  atomicAdd(kvp+0, a0);
  atomicAdd(kvp+1, a1);
  atomicAdd(kvp+2, a2);
  atomicAdd(kvp+3, a3);
  if ((t & 7) == 0) atomicAdd(Ksum + (((n<<3)+h)<<5) + d, ks);
}

// ---------- attention phase B: 16 rows/block, KV cached in LDS (R0 proven) ----------
__global__ __launch_bounds__(256) void attn_apply(const unsigned short* __restrict__ qq,
                                                  const float* __restrict__ KV,
                                                  const float* __restrict__ Ksum,
                                                  unsigned short* __restrict__ msg){
  __shared__ float kvs[8192];   // [h][dd][w]
  __shared__ float kss[256];    // [h][dd]
  __shared__ float Qs[4096];    // [r][256], phi-applied
  const int t = threadIdx.x;
  const int n = blockIdx.y;
  const int row0 = blockIdx.x << 4;
  const size_t boff = (size_t)n * PERBATCH;

  #pragma unroll
  for (int i = 0; i < 32; i++) kvs[i*256 + t] = KV[(size_t)n*8192 + i*256 + t];
  kss[t] = Ksum[n*256 + t];
  #pragma unroll
  for (int r = 0; r < 16; r++)
    Qs[r*256 + t] = phi(bf2f(qq[boff + (size_t)(row0 + r)*256 + t]));
  __syncthreads();

  const int h = t >> 5, w = t & 31;
  const float* kvh = kvs + h*1024;
  const float* ksh = kss + h*32;
  float acc[16], den[16];
  #pragma unroll
  for (int r = 0; r < 16; r++){ acc[r] = 0.f; den[r] = 1e-6f; }

  #pragma unroll
  for (int d4 = 0; d4 < 8; d4++){
    const float k0 = kvh[(d4*4+0)*32 + w];
    const float k1 = kvh[(d4*4+1)*32 + w];
    const float k2 = kvh[(d4*4+2)*32 + w];
    const float k3 = kvh[(d4*4+3)*32 + w];
    const float s0 = ksh[d4*4+0], s1 = ksh[d4*4+1], s2 = ksh[d4*4+2], s3 = ksh[d4*4+3];
    #pragma unroll
    for (int r = 0; r < 16; r++){
      float4 qv = *(const float4*)&Qs[r*256 + h*32 + d4*4];
      acc[r] += qv.x*k0 + qv.y*k1 + qv.z*k2 + qv.w*k3;
      den[r] += qv.x*s0 + qv.y*s1 + qv.z*s2 + qv.w*s3;
    }
  }
  #pragma unroll
  for (int r = 0; r < 16; r++)
    msg[boff + (size_t)(row0 + r)*256 + t] = f2bf(acc[r]/den[r]);
}

// ---------- elementwise ----------
__global__ __launch_bounds__(256) void fill_hcat(const float* __restrict__ x, unsigned short* __restrict__ hcat){
  size_t i = (size_t)blockIdx.x*256 + threadIdx.x;
  hcat[(i >> 8)*512 + (i & 255)] = f2bf(x[i]);
}
__global__ __launch_bounds__(256) void xmid_k(const float* __restrict__ x, const float* __restrict__ macc,
                                              float* __restrict__ xmid, unsigned short* __restrict__ hcat){
  size_t i = (size_t)blockIdx.x*256 + threadIdx.x;
  float v = x[i] + 0.5f*macc[i];
  xmid[i] = v;
  hcat[(i >> 8)*512 + (i & 255)] = f2bf(v);
}
__global__ __launch_bounds__(256) void final_k(float* __restrict__ out, const float* __restrict__ macc){
  size_t i = (size_t)blockIdx.x*256 + threadIdx.x;
  out[i] = out[i] + 0.5f*macc[i];
}
__global__ __launch_bounds__(256) void zero_k(float* __restrict__ p, int n){
  int i = blockIdx.x*256 + threadIdx.x;
  if (i < n) p[i] = 0.f;
}

// ---------- orchestration ----------
extern "C" void kernel_launch(void* const* d_in, const int* in_sizes, int n_in,
                              void* d_out, int out_size, void* d_ws, size_t ws_size,
                              hipStream_t stream){
  const float* x   = (const float*)d_in[0];
  const float* src = (const float*)d_in[1];
  const float* Wq  = (const float*)d_in[2];
  const float* Wk  = (const float*)d_in[3];
  const float* Wv  = (const float*)d_in[4];
  const float* Wm  = (const float*)d_in[5];
  const float* W1  = (const float*)d_in[6];
  const float* W2  = (const float*)d_in[7];
  const float* g1  = (const float*)d_in[8];
  const float* b1  = (const float*)d_in[9];
  const float* g2  = (const float*)d_in[10];
  const float* b2  = (const float*)d_in[11];
  float* out = (float*)d_out;

  char* ws = (char*)d_ws;
  size_t off = 0;
  auto alloc = [&](size_t bytes) -> void* {
    void* p = ws + off;
    off += (bytes + 255) & ~(size_t)255;
    return p;
  };
  unsigned short* qB    = (unsigned short*)alloc((size_t)MROWS*256*2);
  unsigned short* kB    = (unsigned short*)alloc((size_t)MROWS*256*2);
  unsigned short* vB    = (unsigned short*)alloc((size_t)MROWS*256*2);
  unsigned short* hcatB = (unsigned short*)alloc((size_t)MROWS*512*2);
  float* t1   = (float*)alloc((size_t)MROWS*256*4);
  float* macc = (float*)alloc((size_t)MROWS*256*4);
  float* KV4  = (float*)alloc((size_t)4*KVSET*4);
  unsigned short* WqT = (unsigned short*)alloc((size_t)256*256*2);
  unsigned short* WkT = (unsigned short*)alloc((size_t)256*256*2);
  unsigned short* WvT = (unsigned short*)alloc((size_t)256*256*2);
  unsigned short* WmT = (unsigned short*)alloc((size_t)256*256*2);
  unsigned short* W1T = (unsigned short*)alloc((size_t)512*512*2);
  unsigned short* W2T = (unsigned short*)alloc((size_t)256*512*2);
  (void)ws_size; (void)in_sizes; (void)n_in; (void)out_size;

  unsigned short* msgB  = kB;
  unsigned short* hidB  = kB;
  unsigned short* srcbf = (unsigned short*)t1;
  unsigned short* xbf   = srcbf + (size_t)MROWS*256;
  unsigned short* qP    = (unsigned short*)t1;
  unsigned short* kP    = (unsigned short*)macc;
  unsigned short* vP    = kP + (size_t)MROWS*256;
  float* xmid = out;

  const dim3 blk(256);

  wconv<<<dim3(256),  blk, 0, stream>>>(Wq, WqT, 8, 256);
  wconv<<<dim3(256),  blk, 0, stream>>>(Wk, WkT, 8, 256);
  wconv<<<dim3(256),  blk, 0, stream>>>(Wv, WvT, 8, 256);
  wconv<<<dim3(256),  blk, 0, stream>>>(Wm, WmT, 8, 256);
  wconv<<<dim3(1024), blk, 0, stream>>>(W1, W1T, 9, 512);
  wconv<<<dim3(512),  blk, 0, stream>>>(W2, W2T, 9, 256);
  conv_bf16<<<dim3(9600), blk, 0, stream>>>(src, srcbf);
  conv_bf16<<<dim3(9600), blk, 0, stream>>>(x,   xbf);

  gemm_mfma<unsigned short, false><<<dim3(2,300), blk, 0, stream>>>(xbf,   WqT, qB, MROWS, 256, 256);
  gemm_mfma<unsigned short, false><<<dim3(2,300), blk, 0, stream>>>(srcbf, WkT, kB, MROWS, 256, 256);
  gemm_mfma<unsigned short, false><<<dim3(2,300), blk, 0, stream>>>(srcbf, WvT, vB, MROWS, 256, 256);

  zero_k<<<dim3(1056), blk, 0, stream>>>(KV4, 4*KVSET);
  attn_stats<<<dim3(20,8,8), blk, 0, stream>>>(kB, vB, KV4 + 0*KVSET, KV4 + 0*KVSET + 65536);
  permute1<<<dim3(9600,1,2), blk, 0, stream>>>(kB, kP, vB, vP);
  attn_stats<<<dim3(20,8,8), blk, 0, stream>>>(kP, vP, KV4 + 1*KVSET, KV4 + 1*KVSET + 65536);
  permute2<<<dim3(75,8,2),  blk, 0, stream>>>(kB, kP, vB, vP);
  attn_stats<<<dim3(20,8,8), blk, 0, stream>>>(kP, vP, KV4 + 2*KVSET, KV4 + 2*KVSET + 65536);
  permute3<<<dim3(75,8,2),  blk, 0, stream>>>(kB, kP, vB, vP);
  attn_stats<<<dim3(20,8,8), blk, 0, stream>>>(kP, vP, KV4 + 3*KVSET, KV4 + 3*KVSET + 65536);

  fill_hcat<<<dim3(MROWS), blk, 0, stream>>>(x, hcatB);

  auto run_block = [&](int mode, int add){
    const float* KV   = KV4 + (size_t)mode*KVSET;
    const float* Ksum = KV + 65536;
    const unsigned short* qsrc = qB;
    if (mode == 1){ permute1<<<dim3(9600,1,1), blk, 0, stream>>>(qB, qP, nullptr, nullptr); qsrc = qP; }
    else if (mode == 2){ permute2<<<dim3(75,8,1), blk, 0, stream>>>(qB, qP, nullptr, nullptr); qsrc = qP; }
    else if (mode == 3){ permute3<<<dim3(75,8,1), blk, 0, stream>>>(qB, qP, nullptr, nullptr); qsrc = qP; }
    attn_apply<<<dim3(300,BS), blk, 0, stream>>>(qsrc, KV, Ksum, msgB);
    gemm_ln<0><<<dim3(600), blk, 0, stream>>>(msgB, WmT, g1, b1, hcatB, nullptr, 256, 0);
    gemm_mfma<unsigned short, true><<<dim3(4,300), blk, 0, stream>>>(hcatB, W1T, hidB, MROWS, 512, 512);
    gemm_ln<1><<<dim3(600), blk, 0, stream>>>(hidB, W2T, g2, b2, nullptr, macc, 512, add);
  };

  run_block(0, 0);   // m   (identity)
  run_block(1, 1);   // m3  (p13)
  xmid_k<<<dim3(MROWS), blk, 0, stream>>>(x, macc, xmid, hcatB);
  run_block(2, 0);   // m1  (p21)
  run_block(3, 1);   // m2  (p32)
  final_k<<<dim3(MROWS), blk, 0, stream>>>(out, macc);
}

// Round 7
// 979.885 us; speedup vs baseline: 1.4090x; 1.0316x over previous
//
#include <hip/hip_runtime.h>
#include <type_traits>
#include <cstdint>
#include <cstddef>

#define L_SEQ 4800
#define DMODEL 256
#define BS 8
#define MROWS (BS*L_SEQ)          // 38400
#define PERBATCH (L_SEQ*DMODEL)   // 1228800
#define KVSET 67584               // 65536 KV + 2048 Ksum floats per mode

typedef __attribute__((ext_vector_type(8))) short bfrag8;
typedef __attribute__((ext_vector_type(4))) float floatx4;

// ---------- helpers ----------
__device__ __forceinline__ float bf2f(unsigned short u){
  union { unsigned int i; float f; } x; x.i = ((unsigned int)u) << 16; return x.f;
}
__device__ __forceinline__ unsigned short f2bf(float f){
  union { float f; unsigned int i; } x; x.f = f;
  x.i += 0x7fff + ((x.i >> 16) & 1);   // RNE
  return (unsigned short)(x.i >> 16);
}
__device__ __forceinline__ float phi(float x){
  return x > 0.f ? x + 1.f : __expf(x);
}
__device__ __forceinline__ void gll16(const void* g, void* l){
  __builtin_amdgcn_global_load_lds((const __attribute__((address_space(1))) unsigned int*)g,
      (__attribute__((address_space(3))) unsigned int*)l, 16, 0, 0);
}

// ---------- MFMA GEMM (projections): C[M,N] = A[M,K] @ Bt[N,K]^T ----------
template<typename TC, bool RELU>
__global__ __launch_bounds__(256) void gemm_mfma(const unsigned short* __restrict__ A,
                                                 const unsigned short* __restrict__ Bt,
                                                 TC* __restrict__ C, int M, int N, int K){
  __shared__ unsigned short Al[2][4096];   // [buf][128 rows][32 k]
  __shared__ unsigned short Bl[2][4096];
  const int tid  = threadIdx.x;
  const int lane = tid & 63;
  const int wave = tid >> 6;
  const int row0 = blockIdx.y << 7;
  const int col0 = blockIdx.x << 7;
  const int wr0  = (wave & 1) << 6;
  const int wc0  = (wave >> 1) << 6;
  const int m = lane & 15, q = lane >> 4;
  const int sw = (m >> 1) & 3;

  floatx4 acc[4][4] = {};

  const int u0 = tid, u1 = tid + 256;
  const int r0 = u0 >> 2, s0 = u0 & 3;
  const int r1 = u1 >> 2, s1 = u1 & 3;

  auto stage = [&](int k0, int b){
    gll16(A  + (size_t)(row0 + r0)*K + k0 + ((s0 ^ ((r0 >> 1) & 3)) << 3), Al[b] + (size_t)u0*8);
    gll16(A  + (size_t)(row0 + r1)*K + k0 + ((s1 ^ ((r1 >> 1) & 3)) << 3), Al[b] + (size_t)u1*8);
    gll16(Bt + (size_t)(col0 + r0)*K + k0 + ((s0 ^ ((r0 >> 1) & 3)) << 3), Bl[b] + (size_t)u0*8);
    gll16(Bt + (size_t)(col0 + r1)*K + k0 + ((s1 ^ ((r1 >> 1) & 3)) << 3), Bl[b] + (size_t)u1*8);
  };

  stage(0, 0);
  const int nk = K >> 5;
  for (int ks = 0; ks < nk; ks++){
    asm volatile("s_waitcnt vmcnt(0) lgkmcnt(0)" ::: "memory");
    __builtin_amdgcn_s_barrier();
    asm volatile("" ::: "memory");
    if (ks < nk - 1) stage((ks + 1) << 5, (ks + 1) & 1);
    const unsigned short* ab = Al[ks & 1];
    const unsigned short* bb = Bl[ks & 1];
    bfrag8 af[4], bf[4];
    #pragma unroll
    for (int t = 0; t < 4; t++){
      af[t] = *(const bfrag8*)(ab + (size_t)(wr0 + t*16 + m)*32 + ((q ^ sw) << 3));
      bf[t] = *(const bfrag8*)(bb + (size_t)(wc0 + t*16 + m)*32 + ((q ^ sw) << 3));
    }
    #pragma unroll
    for (int mt = 0; mt < 4; mt++)
      #pragma unroll
      for (int nt = 0; nt < 4; nt++)
        acc[mt][nt] = __builtin_amdgcn_mfma_f32_16x16x32_bf16(af[mt], bf[nt], acc[mt][nt], 0, 0, 0);
  }

  #pragma unroll
  for (int mt = 0; mt < 4; mt++){
    #pragma unroll
    for (int nt = 0; nt < 4; nt++){
      const int col  = col0 + wc0 + nt*16 + m;
      const int rowb = row0 + wr0 + mt*16 + q*4;
      #pragma unroll
      for (int i = 0; i < 4; i++){
        float v = acc[mt][nt][i];
        if (RELU) v = v > 0.f ? v : 0.f;
        if constexpr (std::is_same<TC,float>::value) C[(size_t)(rowb+i)*N + col] = v;
        else                                         C[(size_t)(rowb+i)*N + col] = f2bf(v);
      }
    }
  }
}

// ---------- W1 GEMM with K-split A: hid = relu([xc | msgln] @ W1) ----------
// Identical proven structure to gemm_mfma; only the A source switches at k=256.
__global__ __launch_bounds__(256) void gemm_w1(const unsigned short* __restrict__ Axc,
                                               const unsigned short* __restrict__ Amsg,
                                               const unsigned short* __restrict__ Bt,
                                               unsigned short* __restrict__ C){
  __shared__ unsigned short Al[2][4096];
  __shared__ unsigned short Bl[2][4096];
  const int tid  = threadIdx.x;
  const int lane = tid & 63;
  const int wave = tid >> 6;
  const int row0 = blockIdx.y << 7;
  const int col0 = blockIdx.x << 7;
  const int wr0  = (wave & 1) << 6;
  const int wc0  = (wave >> 1) << 6;
  const int m = lane & 15, q = lane >> 4;
  const int sw = (m >> 1) & 3;
  const int K = 512;

  floatx4 acc[4][4] = {};

  const int u0 = tid, u1 = tid + 256;
  const int r0 = u0 >> 2, s0 = u0 & 3;
  const int r1 = u1 >> 2, s1 = u1 & 3;

  auto stage = [&](int ks, int b){
    const int k0 = ks << 5;
    const unsigned short* As = (ks < 8) ? Axc : Amsg;
    const int kk = k0 & 255;
    gll16(As + (size_t)(row0 + r0)*256 + kk + ((s0 ^ ((r0 >> 1) & 3)) << 3), Al[b] + (size_t)u0*8);
    gll16(As + (size_t)(row0 + r1)*256 + kk + ((s1 ^ ((r1 >> 1) & 3)) << 3), Al[b] + (size_t)u1*8);
    gll16(Bt + (size_t)(col0 + r0)*K + k0 + ((s0 ^ ((r0 >> 1) & 3)) << 3), Bl[b] + (size_t)u0*8);
    gll16(Bt + (size_t)(col0 + r1)*K + k0 + ((s1 ^ ((r1 >> 1) & 3)) << 3), Bl[b] + (size_t)u1*8);
  };

  stage(0, 0);
  for (int ks = 0; ks < 16; ks++){
    asm volatile("s_waitcnt vmcnt(0) lgkmcnt(0)" ::: "memory");
    __builtin_amdgcn_s_barrier();
    asm volatile("" ::: "memory");
    if (ks < 15) stage(ks + 1, (ks + 1) & 1);
    const unsigned short* ab = Al[ks & 1];
    const unsigned short* bb = Bl[ks & 1];
    bfrag8 af[4], bf[4];
    #pragma unroll
    for (int t = 0; t < 4; t++){
      af[t] = *(const bfrag8*)(ab + (size_t)(wr0 + t*16 + m)*32 + ((q ^ sw) << 3));
      bf[t] = *(const bfrag8*)(bb + (size_t)(wc0 + t*16 + m)*32 + ((q ^ sw) << 3));
    }
    #pragma unroll
    for (int mt = 0; mt < 4; mt++)
      #pragma unroll
      for (int nt = 0; nt < 4; nt++)
        acc[mt][nt] = __builtin_amdgcn_mfma_f32_16x16x32_bf16(af[mt], bf[nt], acc[mt][nt], 0, 0, 0);
  }

  #pragma unroll
  for (int mt = 0; mt < 4; mt++){
    #pragma unroll
    for (int nt = 0; nt < 4; nt++){
      const int col  = col0 + wc0 + nt*16 + m;
      const int rowb = row0 + wr0 + mt*16 + q*4;
      #pragma unroll
      for (int i = 0; i < 4; i++){
        float v = acc[mt][nt][i];
        v = v > 0.f ? v : 0.f;
        C[(size_t)(rowb+i)*512 + col] = f2bf(v);
      }
    }
  }
}

// ---------- GEMM + LN, BK=64, single-buffered, 64x256 tile ----------
// LDS half-tiles keep the proven 32-short-row + (r>>1)&3 slot swizzle.
// MODE 0: z-paired (blockIdx.y selects A/out); out = contiguous bf16 msgln rows.
// MODE 1: outf[row*256+col] (+)= LN(...)
template<int MODE>
__global__ __launch_bounds__(256) void gemm_lnv2(const unsigned short* __restrict__ A0,
                                                 const unsigned short* __restrict__ A1,
                                                 const unsigned short* __restrict__ Bt,
                                                 const float* __restrict__ g,
                                                 const float* __restrict__ b,
                                                 unsigned short* __restrict__ ob0,
                                                 unsigned short* __restrict__ ob1,
                                                 float* __restrict__ of,
                                                 int K, int add){
  __shared__ unsigned short Ab[4096];     // 2 half-tiles x [64 r][32 k]
  __shared__ unsigned short Bb[16384];    // 2 half-tiles x [256 c][32 k]
  __shared__ float2 LNp[64][4];
  __shared__ float2 LNmu[64];
  const int tid = threadIdx.x;
  const int wv = tid >> 6, lane = tid & 63;
  const int m = lane & 15, qd = lane >> 4;
  const int sw = (m >> 1) & 3;
  const int row0 = blockIdx.x << 6;
  const unsigned short* A = (MODE == 0 && blockIdx.y) ? A1 : A0;
  unsigned short* ob = (MODE == 0 && blockIdx.y) ? ob1 : ob0;

  floatx4 acc[4][4] = {};
  const int nsteps = K >> 6;
  for (int o = 0; o < nsteps; o++){
    const int k0 = o << 6;
    #pragma unroll
    for (int i = 0; i < 2; i++){           // A: u in [0,512): [h][r][s]
      int u = (i << 8) + tid;
      int r = (u & 255) >> 2, s = u & 3, h = u >> 8;
      gll16(A + (size_t)(row0 + r)*K + k0 + h*32 + ((s ^ ((r >> 1) & 3)) << 3),
            Ab + (size_t)u*8);
    }
    #pragma unroll
    for (int i = 0; i < 8; i++){           // B: u in [0,2048): [h][c][s]
      int u = (i << 8) + tid;
      int c = (u & 1023) >> 2, s = u & 3, h = u >> 10;
      gll16(Bt + (size_t)c*K + k0 + h*32 + ((s ^ ((c >> 1) & 3)) << 3),
            Bb + (size_t)u*8);
    }
    asm volatile("s_waitcnt vmcnt(0)" ::: "memory");
    __syncthreads();
    #pragma unroll
    for (int j = 0; j < 2; j++){
      bfrag8 af[4], bf[4];
      #pragma unroll
      for (int mt = 0; mt < 4; mt++){
        int r = mt*16 + m;
        af[mt] = *(const bfrag8*)(Ab + (size_t)j*2048 + (size_t)r*32 + ((qd ^ sw) << 3));
      }
      #pragma unroll
      for (int nt = 0; nt < 4; nt++){
        int c = wv*64 + nt*16 + m;
        bf[nt] = *(const bfrag8*)(Bb + (size_t)j*8192 + (size_t)c*32 + ((qd ^ sw) << 3));
      }
      #pragma unroll
      for (int mt = 0; mt < 4; mt++)
        #pragma unroll
        for (int nt = 0; nt < 4; nt++)
          acc[mt][nt] = __builtin_amdgcn_mfma_f32_16x16x32_bf16(af[mt], bf[nt], acc[mt][nt], 0, 0, 0);
    }
    __syncthreads();
  }

  // ---- LN: per-wave partials over its 64 cols, merge across 4 waves ----
  #pragma unroll
  for (int mt = 0; mt < 4; mt++)
    #pragma unroll
    for (int i = 0; i < 4; i++){
      float s = 0.f, q = 0.f;
      #pragma unroll
      for (int nt = 0; nt < 4; nt++){ float v = acc[mt][nt][i]; s += v; q += v*v; }
      #pragma unroll
      for (int o = 1; o < 16; o <<= 1){ s += __shfl_xor(s, o, 64); q += __shfl_xor(q, o, 64); }
      if (m == 0) LNp[mt*16 + qd*4 + i][wv] = make_float2(s, q);
    }
  __syncthreads();
  if (tid < 64){
    float2 p0 = LNp[tid][0], p1 = LNp[tid][1], p2 = LNp[tid][2], p3 = LNp[tid][3];
    float S = p0.x + p1.x + p2.x + p3.x;
    float Q = p0.y + p1.y + p2.y + p3.y;
    float mean = S * (1.f/256.f);
    float var  = Q * (1.f/256.f) - mean*mean;
    LNmu[tid] = make_float2(mean, rsqrtf(var + 1e-5f));
  }
  __syncthreads();

  float gv[4], bv[4];
  #pragma unroll
  for (int nt = 0; nt < 4; nt++){ int col = wv*64 + nt*16 + m; gv[nt] = g[col]; bv[nt] = b[col]; }
  #pragma unroll
  for (int mt = 0; mt < 4; mt++)
    #pragma unroll
    for (int i = 0; i < 4; i++){
      int row = mt*16 + qd*4 + i;
      float2 ms = LNmu[row];
      const size_t rowg = row0 + row;
      #pragma unroll
      for (int nt = 0; nt < 4; nt++){
        int col = wv*64 + nt*16 + m;
        float y = (acc[mt][nt][i] - ms.x) * ms.y * gv[nt] + bv[nt];
        if constexpr (MODE == 0){
          ob[rowg*256 + col] = f2bf(y);
        } else {
          float* p = of + rowg*256 + col;
          if (add) y += *p;
          *p = y;
        }
      }
    }
}

// ---------- one-time converts ----------
__global__ __launch_bounds__(256) void wconv(const float* __restrict__ W, unsigned short* __restrict__ Wt,
                                             int kshift, int N){
  int idx = blockIdx.x*256 + threadIdx.x;
  int kk = idx & ((1 << kshift) - 1);
  int nn = idx >> kshift;
  Wt[idx] = f2bf(W[(size_t)kk*N + nn]);
}
__global__ __launch_bounds__(256) void conv_bf16(const float* __restrict__ in, unsigned short* __restrict__ out){
  int i = blockIdx.x*256 + threadIdx.x;
  float4 v = ((const float4*)in)[i];
  ushort4 o; o.x = f2bf(v.x); o.y = f2bf(v.y); o.z = f2bf(v.z); o.w = f2bf(v.w);
  ((ushort4*)out)[i] = o;
}

// ---------- permute materializers ----------
__global__ __launch_bounds__(256) void permute1(const unsigned short* __restrict__ sA, unsigned short* __restrict__ dA,
                                                const unsigned short* __restrict__ sB, unsigned short* __restrict__ dB){
  const unsigned short* s = blockIdx.z ? sB : sA;
  unsigned short*       d = blockIdx.z ? dB : dA;
  __shared__ unsigned short tile[1024];
  const int t = threadIdx.x;
  const size_t base = (size_t)blockIdx.x * 1024;
  #pragma unroll
  for (int i = 0; i < 4; i++) tile[i*256 + t] = s[base + i*256 + t];
  __syncthreads();
  const int pg = ((t & 7) << 5) + (t >> 3);
  #pragma unroll
  for (int i = 0; i < 4; i++) d[base + i*256 + t] = tile[i*256 + pg];
}

__global__ __launch_bounds__(256) void permute2(const unsigned short* __restrict__ sA, unsigned short* __restrict__ dA,
                                                const unsigned short* __restrict__ sB, unsigned short* __restrict__ dB){
  const unsigned short* s = blockIdx.z ? sB : sA;
  unsigned short*       d = blockIdx.z ? dB : dA;
  __shared__ unsigned short tile[64*256];
  const int t = threadIdx.x;
  const int rr0 = blockIdx.x * 64;
  const size_t boff = (size_t)blockIdx.y * PERBATCH;
  #pragma unroll
  for (int i = 0; i < 16; i++){
    int u = i*256 + t;
    *(ushort4*)&tile[u*4] = *(const ushort4*)&s[boff + (size_t)rr0*256 + (size_t)u*4];
  }
  __syncthreads();
  #pragma unroll
  for (int i = 0; i < 8; i++){
    #pragma unroll
    for (int w = 0; w < 2; w++){
      int u = w*256 + t;
      int rr = u >> 3, c4 = (u & 7) << 2;
      ushort4 v = *(const ushort4*)&tile[rr*256 + i*32 + c4];
      *(ushort4*)&d[boff + (size_t)i*153600 + (size_t)rr0*32 + (size_t)u*4] = v;
    }
  }
}

__global__ __launch_bounds__(256) void permute3(const unsigned short* __restrict__ sA, unsigned short* __restrict__ dA,
                                                const unsigned short* __restrict__ sB, unsigned short* __restrict__ dB){
  const unsigned short* s = blockIdx.z ? sB : sA;
  unsigned short*       d = blockIdx.z ? dB : dA;
  __shared__ unsigned short tile[64*258];
  const int t = threadIdx.x;
  const int ll0 = blockIdx.x * 64;
  const size_t boff = (size_t)blockIdx.y * PERBATCH;
  #pragma unroll
  for (int i = 0; i < 32; i++){
    int u = i*256 + t;
    int row = u >> 7, col = (u & 127) << 1;
    *(ushort2*)&tile[row*258 + col] = *(const ushort2*)&s[boff + (size_t)(ll0+row)*256 + col];
  }
  __syncthreads();
  const int cw = t >> 6;
  const int ll = t & 63;
  #pragma unroll
  for (int cc = 0; cc < 256; cc += 4){
    int c = cc + cw;
    int sigma = ((c & 31) << 3) + (c >> 5);
    d[boff + (size_t)sigma*4800 + ll0 + ll] = tile[ll*258 + c];
  }
}

// ---------- attention phase A (KV/Ksum stats) ----------
__global__ __launch_bounds__(256) void attn_stats(const unsigned short* __restrict__ kq,
                                                  const unsigned short* __restrict__ vq,
                                                  float* __restrict__ KV, float* __restrict__ Ksum){
  const int chunk = blockIdx.x, h = blockIdx.y, n = blockIdx.z;
  const int t = threadIdx.x;
  const int d = t >> 3;
  const int w4 = (t & 7) << 2;
  const size_t boff = (size_t)n * PERBATCH;
  __shared__ float kb[8][32], vb[8][32];
  const int lr = t >> 5, lj = t & 31;
  float a0=0.f, a1=0.f, a2=0.f, a3=0.f, ks=0.f;
  const int s0 = chunk * 240;
  for (int s = s0; s < s0 + 240; s += 8){
    int srci = (s + lr)*256 + (h << 5) + lj;
    kb[lr][lj] = phi(bf2f(kq[boff + srci]));
    vb[lr][lj] = bf2f(vq[boff + srci]);
    __syncthreads();
    #pragma unroll
    for (int r = 0; r < 8; r++){
      float kd = kb[r][d];
      ks += kd;
      a0 += kd * vb[r][w4+0];
      a1 += kd * vb[r][w4+1];
      a2 += kd * vb[r][w4+2];
      a3 += kd * vb[r][w4+3];
    }
    __syncthreads();
  }
  float* kvp = KV + (size_t)((((n<<3)+h)<<5) + d)*32 + w4;
  atomicAdd(kvp+0, a0);
  atomicAdd(kvp+1, a1);
  atomicAdd(kvp+2, a2);
  atomicAdd(kvp+3, a3);
  if ((t & 7) == 0) atomicAdd(Ksum + (((n<<3)+h)<<5) + d, ks);
}

// ---------- attention phase B: 16 rows/block, KV cached in LDS (R0 proven) ----------
__global__ __launch_bounds__(256) void attn_apply(const unsigned short* __restrict__ qq,
                                                  const float* __restrict__ KV,
                                                  const float* __restrict__ Ksum,
                                                  unsigned short* __restrict__ msg){
  __shared__ float kvs[8192];   // [h][dd][w]
  __shared__ float kss[256];    // [h][dd]
  __shared__ float Qs[4096];    // [r][256], phi-applied
  const int t = threadIdx.x;
  const int n = blockIdx.y;
  const int row0 = blockIdx.x << 4;
  const size_t boff = (size_t)n * PERBATCH;

  #pragma unroll
  for (int i = 0; i < 32; i++) kvs[i*256 + t] = KV[(size_t)n*8192 + i*256 + t];
  kss[t] = Ksum[n*256 + t];
  #pragma unroll
  for (int r = 0; r < 16; r++)
    Qs[r*256 + t] = phi(bf2f(qq[boff + (size_t)(row0 + r)*256 + t]));
  __syncthreads();

  const int h = t >> 5, w = t & 31;
  const float* kvh = kvs + h*1024;
  const float* ksh = kss + h*32;
  float acc[16], den[16];
  #pragma unroll
  for (int r = 0; r < 16; r++){ acc[r] = 0.f; den[r] = 1e-6f; }

  #pragma unroll
  for (int d4 = 0; d4 < 8; d4++){
    const float k0 = kvh[(d4*4+0)*32 + w];
    const float k1 = kvh[(d4*4+1)*32 + w];
    const float k2 = kvh[(d4*4+2)*32 + w];
    const float k3 = kvh[(d4*4+3)*32 + w];
    const float s0 = ksh[d4*4+0], s1 = ksh[d4*4+1], s2 = ksh[d4*4+2], s3 = ksh[d4*4+3];
    #pragma unroll
    for (int r = 0; r < 16; r++){
      float4 qv = *(const float4*)&Qs[r*256 + h*32 + d4*4];
      acc[r] += qv.x*k0 + qv.y*k1 + qv.z*k2 + qv.w*k3;
      den[r] += qv.x*s0 + qv.y*s1 + qv.z*s2 + qv.w*s3;
    }
  }
  #pragma unroll
  for (int r = 0; r < 16; r++)
    msg[boff + (size_t)(row0 + r)*256 + t] = f2bf(acc[r]/den[r]);
}

// ---------- elementwise ----------
__global__ __launch_bounds__(256) void xmid_k(const float* __restrict__ x, const float* __restrict__ macc,
                                              float* __restrict__ xmid, unsigned short* __restrict__ xcbf){
  size_t i = (size_t)blockIdx.x*256 + threadIdx.x;
  float v = x[i] + 0.5f*macc[i];
  xmid[i] = v;
  xcbf[i] = f2bf(v);
}
__global__ __launch_bounds__(256) void final_k(float* __restrict__ out, const float* __restrict__ macc){
  size_t i = (size_t)blockIdx.x*256 + threadIdx.x;
  out[i] = out[i] + 0.5f*macc[i];
}
__global__ __launch_bounds__(256) void zero_k(float* __restrict__ p, int n){
  int i = blockIdx.x*256 + threadIdx.x;
  if (i < n) p[i] = 0.f;
}

// ---------- orchestration ----------
extern "C" void kernel_launch(void* const* d_in, const int* in_sizes, int n_in,
                              void* d_out, int out_size, void* d_ws, size_t ws_size,
                              hipStream_t stream){
  const float* x   = (const float*)d_in[0];
  const float* src = (const float*)d_in[1];
  const float* Wq  = (const float*)d_in[2];
  const float* Wk  = (const float*)d_in[3];
  const float* Wv  = (const float*)d_in[4];
  const float* Wm  = (const float*)d_in[5];
  const float* W1  = (const float*)d_in[6];
  const float* W2  = (const float*)d_in[7];
  const float* g1  = (const float*)d_in[8];
  const float* b1  = (const float*)d_in[9];
  const float* g2  = (const float*)d_in[10];
  const float* b2  = (const float*)d_in[11];
  float* out = (float*)d_out;

  char* ws = (char*)d_ws;
  size_t off = 0;
  auto alloc = [&](size_t bytes) -> void* {
    void* p = ws + off;
    off += (bytes + 255) & ~(size_t)255;
    return p;
  };
  unsigned short* qB   = (unsigned short*)alloc((size_t)MROWS*256*2);
  unsigned short* kB   = (unsigned short*)alloc((size_t)MROWS*256*2);   // msg slot A / hid lo
  unsigned short* vB   = (unsigned short*)alloc((size_t)MROWS*256*2);   // msg slot B / hid hi
  unsigned short* mlnB = (unsigned short*)alloc((size_t)MROWS*512*2);   // msgln0 | msgln1
  float* t1   = (float*)alloc((size_t)MROWS*256*4);                     // srcbf/qP | xbf/xc
  float* macc = (float*)alloc((size_t)MROWS*256*4);
  float* KV4  = (float*)alloc((size_t)4*KVSET*4);
  unsigned short* WqT = (unsigned short*)alloc((size_t)256*256*2);
  unsigned short* WkT = (unsigned short*)alloc((size_t)256*256*2);
  unsigned short* WvT = (unsigned short*)alloc((size_t)256*256*2);
  unsigned short* WmT = (unsigned short*)alloc((size_t)256*256*2);
  unsigned short* W1T = (unsigned short*)alloc((size_t)512*512*2);
  unsigned short* W2T = (unsigned short*)alloc((size_t)256*512*2);
  (void)ws_size; (void)in_sizes; (void)n_in; (void)out_size;

  unsigned short* srcbf  = (unsigned short*)t1;
  unsigned short* xcbf   = srcbf + (size_t)MROWS*256;    // x bf16, later xmid bf16
  unsigned short* qP     = (unsigned short*)t1;          // reuses srcbf slot after projections
  unsigned short* msgln0 = mlnB;
  unsigned short* msgln1 = mlnB + (size_t)MROWS*256;
  unsigned short* hid    = kB;                           // 39.3MB spanning kB+vB
  float* xmid = out;

  const dim3 blk(256);

  wconv<<<dim3(256),  blk, 0, stream>>>(Wq, WqT, 8, 256);
  wconv<<<dim3(256),  blk, 0, stream>>>(Wk, WkT, 8, 256);
  wconv<<<dim3(256),  blk, 0, stream>>>(Wv, WvT, 8, 256);
  wconv<<<dim3(256),  blk, 0, stream>>>(Wm, WmT, 8, 256);
  wconv<<<dim3(1024), blk, 0, stream>>>(W1, W1T, 9, 512);
  wconv<<<dim3(512),  blk, 0, stream>>>(W2, W2T, 9, 256);
  conv_bf16<<<dim3(9600), blk, 0, stream>>>(src, srcbf);
  conv_bf16<<<dim3(9600), blk, 0, stream>>>(x,   xcbf);

  gemm_mfma<unsigned short, false><<<dim3(2,300), blk, 0, stream>>>(xcbf,  WqT, qB, MROWS, 256, 256);
  gemm_mfma<unsigned short, false><<<dim3(2,300), blk, 0, stream>>>(srcbf, WkT, kB, MROWS, 256, 256);
  gemm_mfma<unsigned short, false><<<dim3(2,300), blk, 0, stream>>>(srcbf, WvT, vB, MROWS, 256, 256);

  // all-mode stats upfront; permuted k/v live in macc space (dead until gemm_lnv2<1>)
  unsigned short* kP = (unsigned short*)macc;
  unsigned short* vP = kP + (size_t)MROWS*256;
  zero_k<<<dim3(1056), blk, 0, stream>>>(KV4, 4*KVSET);
  attn_stats<<<dim3(20,8,8), blk, 0, stream>>>(kB, vB, KV4 + 0*KVSET, KV4 + 0*KVSET + 65536);
  permute1<<<dim3(9600,1,2), blk, 0, stream>>>(kB, kP, vB, vP);
  attn_stats<<<dim3(20,8,8), blk, 0, stream>>>(kP, vP, KV4 + 1*KVSET, KV4 + 1*KVSET + 65536);
  permute2<<<dim3(75,8,2),  blk, 0, stream>>>(kB, kP, vB, vP);
  attn_stats<<<dim3(20,8,8), blk, 0, stream>>>(kP, vP, KV4 + 2*KVSET, KV4 + 2*KVSET + 65536);
  permute3<<<dim3(75,8,2),  blk, 0, stream>>>(kB, kP, vB, vP);
  attn_stats<<<dim3(20,8,8), blk, 0, stream>>>(kP, vP, KV4 + 3*KVSET, KV4 + 3*KVSET + 65536);

  auto run_pair = [&](int modeA, int modeB, int addA){
    // attention for both modes of the pair -> msg in kB / vB
    {
      const float* KV   = KV4 + (size_t)modeA*KVSET;
      const unsigned short* qsrc = qB;
      if (modeA == 2){ permute2<<<dim3(75,8,1), blk, 0, stream>>>(qB, qP, nullptr, nullptr); qsrc = qP; }
      attn_apply<<<dim3(300,BS), blk, 0, stream>>>(qsrc, KV, KV + 65536, kB);
    }
    {
      const float* KV   = KV4 + (size_t)modeB*KVSET;
      if (modeB == 1)      permute1<<<dim3(9600,1,1), blk, 0, stream>>>(qB, qP, nullptr, nullptr);
      else                 permute3<<<dim3(75,8,1),   blk, 0, stream>>>(qB, qP, nullptr, nullptr);
      attn_apply<<<dim3(300,BS), blk, 0, stream>>>(qP, KV, KV + 65536, vB);
    }
    // merged Wm GEMM + LN for both modes -> msgln0/msgln1
    gemm_lnv2<0><<<dim3(600,2), blk, 0, stream>>>(kB, vB, WmT, g1, b1, msgln0, msgln1, nullptr, 256, 0);
    // FFN chains (serial: hid buffer shared)
    gemm_w1<<<dim3(4,300), blk, 0, stream>>>(xcbf, msgln0, W1T, hid);
    gemm_lnv2<1><<<dim3(600,1), blk, 0, stream>>>(hid, nullptr, W2T, g2, b2, nullptr, nullptr, macc, 512, addA);
    gemm_w1<<<dim3(4,300), blk, 0, stream>>>(xcbf, msgln1, W1T, hid);
    gemm_lnv2<1><<<dim3(600,1), blk, 0, stream>>>(hid, nullptr, W2T, g2, b2, nullptr, nullptr, macc, 512, 1);
  };

  run_pair(0, 1, 0);                                            // m, m3
  xmid_k<<<dim3(MROWS), blk, 0, stream>>>(x, macc, xmid, xcbf); // xmid + xc update
  run_pair(2, 3, 0);                                            // m1, m2
  final_k<<<dim3(MROWS), blk, 0, stream>>>(out, macc);
}